// Round 1
// baseline (837.795 us; speedup 1.0000x reference)
//
#include <hip/hip_runtime.h>

typedef __bf16 bf16;
typedef __bf16 bf16x8 __attribute__((ext_vector_type(8)));
typedef __bf16 bf16x4 __attribute__((ext_vector_type(4)));
typedef float  f32x4  __attribute__((ext_vector_type(4)));

#define LOG2E 1.4426950408889634f

// ---------------------------------------------------------------- helpers
__device__ __forceinline__ void gload_lds16(const void* g, void* l) {
    __builtin_amdgcn_global_load_lds(
        (__attribute__((address_space(1))) const void*)g,
        (__attribute__((address_space(3))) void*)l, 16, 0, 0);
}

// ---------------------------------------------------------------- f32 -> bf16 weight convert
__global__ __launch_bounds__(256) void cvt_bf16(const float* __restrict__ src,
                                                bf16* __restrict__ dst, int n) {
    int i = (blockIdx.x * 256 + threadIdx.x) * 4;
    if (i + 3 < n) {
        float4 v = *(const float4*)(src + i);
        bf16x4 o;
        o[0] = (bf16)v.x; o[1] = (bf16)v.y; o[2] = (bf16)v.z; o[3] = (bf16)v.w;
        *(bf16x4*)(dst + i) = o;
    }
}

// ---------------------------------------------------------------- LayerNorm (f32 in, bf16 out), row = 2048
__global__ __launch_bounds__(256) void ln_kernel(const float* __restrict__ x,
                                                 const float* __restrict__ wgt,
                                                 const float* __restrict__ bias,
                                                 bf16* __restrict__ out) {
    __shared__ float red[8];
    const int tid = threadIdx.x;
    const int lane = tid & 63, w = tid >> 6;
    const size_t row = blockIdx.x;
    const float4* xr = (const float4*)(x + row * 2048);
    float4 v0 = xr[tid];
    float4 v1 = xr[tid + 256];
    float s = v0.x + v0.y + v0.z + v0.w + v1.x + v1.y + v1.z + v1.w;
    float q = v0.x*v0.x + v0.y*v0.y + v0.z*v0.z + v0.w*v0.w
            + v1.x*v1.x + v1.y*v1.y + v1.z*v1.z + v1.w*v1.w;
    #pragma unroll
    for (int off = 32; off; off >>= 1) {
        s += __shfl_xor(s, off);
        q += __shfl_xor(q, off);
    }
    if (lane == 0) { red[w] = s; red[4 + w] = q; }
    __syncthreads();
    float S  = red[0] + red[1] + red[2] + red[3];
    float Q2 = red[4] + red[5] + red[6] + red[7];
    float mu = S * (1.0f / 2048.0f);
    float var = Q2 * (1.0f / 2048.0f) - mu * mu;
    float rstd = rsqrtf(var + 1e-5f);

    bf16* orow = out + row * 2048;
    int c0 = tid * 4;
    float vv[8] = {v0.x, v0.y, v0.z, v0.w, v1.x, v1.y, v1.z, v1.w};
    bf16x4 o;
    #pragma unroll
    for (int k = 0; k < 4; ++k)
        o[k] = (bf16)((vv[k] - mu) * rstd * wgt[c0 + k] + bias[c0 + k]);
    *(bf16x4*)(orow + c0) = o;
    #pragma unroll
    for (int k = 0; k < 4; ++k)
        o[k] = (bf16)((vv[4 + k] - mu) * rstd * wgt[1024 + c0 + k] + bias[1024 + c0 + k]);
    *(bf16x4*)(orow + 1024 + c0) = o;
}

// ---------------------------------------------------------------- GEMM  C[M,N] = A[M,K] * B[N,K]^T  (both bf16)
// EPI: 0 = bf16 out, 1 = +bias, exact GELU, bf16 out, 2 = res + acc -> f32, 3 = res + acc + bias -> f32
template <int EPI>
__global__ __launch_bounds__(256) void gemm_bt(const bf16* __restrict__ A,
                                               const bf16* __restrict__ B,
                                               void* __restrict__ OutP,
                                               const float* __restrict__ bias,
                                               const float* __restrict__ res,
                                               int M, int N, int K) {
    __shared__ __align__(16) bf16 As[128 * 32];
    __shared__ __align__(16) bf16 Bs[128 * 32];
    const int tid = threadIdx.x;
    const int lane = tid & 63;
    const int w = tid >> 6, wr = w >> 1, wc = w & 1;
    const int lo = lane & 15, hi = lane >> 4;
    const int brow = blockIdx.y * 128, bcol = blockIdx.x * 128;

    const int r0 = tid >> 2, c0 = (tid & 3) * 8;
    const bf16* Ag = A + (size_t)(brow + r0) * K + c0;
    const bf16* Bg = B + (size_t)(bcol + r0) * K + c0;
    char* asb = (char*)As + tid * 16;
    char* bsb = (char*)Bs + tid * 16;

    f32x4 acc[4][4] = {};

    for (int k0 = 0; k0 < K; k0 += 32) {
        gload_lds16(Ag + k0, asb);
        gload_lds16(Ag + (size_t)64 * K + k0, asb + 4096);
        gload_lds16(Bg + k0, bsb);
        gload_lds16(Bg + (size_t)64 * K + k0, bsb + 4096);
        __syncthreads();
        bf16x8 af[4], bfv[4];
        const char* ab = (const char*)As + (wr * 64 + lo) * 64 + hi * 16;
        const char* bb = (const char*)Bs + (wc * 64 + lo) * 64 + hi * 16;
        #pragma unroll
        for (int m = 0; m < 4; ++m) af[m] = *(const bf16x8*)(ab + m * 1024);
        #pragma unroll
        for (int n = 0; n < 4; ++n) bfv[n] = *(const bf16x8*)(bb + n * 1024);
        #pragma unroll
        for (int m = 0; m < 4; ++m)
            #pragma unroll
            for (int n = 0; n < 4; ++n)
                acc[m][n] = __builtin_amdgcn_mfma_f32_16x16x32_bf16(af[m], bfv[n], acc[m][n], 0, 0, 0);
        __syncthreads();
    }

    float* outF = (float*)OutP;
    bf16*  outB = (bf16*)OutP;
    #pragma unroll
    for (int n = 0; n < 4; ++n) {
        const int col = bcol + wc * 64 + n * 16 + lo;
        float bv = 0.f;
        if (EPI == 1 || EPI == 3) bv = bias[col];
        #pragma unroll
        for (int m = 0; m < 4; ++m) {
            #pragma unroll
            for (int r = 0; r < 4; ++r) {
                const int row = brow + wr * 64 + m * 16 + hi * 4 + r;
                float v = acc[m][n][r];
                if (EPI == 0) {
                    outB[(size_t)row * N + col] = (bf16)v;
                } else if (EPI == 1) {
                    v += bv;
                    v = 0.5f * v * (1.0f + erff(v * 0.70710678118654752f));
                    outB[(size_t)row * N + col] = (bf16)v;
                } else if (EPI == 2) {
                    outF[(size_t)row * N + col] = res[(size_t)row * N + col] + v;
                } else {
                    outF[(size_t)row * N + col] = res[(size_t)row * N + col] + v + bv;
                }
            }
        }
    }
}

// ---------------------------------------------------------------- RoPE + GQA scatter
// qkv: (B*T, 3072) bf16  ->  Q (B,16,T,128), K (B,4,T,128), Vt (B,4,128,T)
__global__ __launch_bounds__(256) void rope_scatter(const bf16* __restrict__ qkv,
                                                    const float* __restrict__ cosb,
                                                    const float* __restrict__ sinb,
                                                    bf16* __restrict__ Q,
                                                    bf16* __restrict__ Kg,
                                                    bf16* __restrict__ Vt) {
    const int tid = threadIdx.x;
    const int row = blockIdx.x;          // b*T + t
    const int b = row >> 11, t = row & 2047;
    const bf16* src = qkv + (size_t)row * 3072;
    for (int i = tid; i < 1536; i += 256) {
        int slot = i >> 6;               // 0..23  = g*6 + m
        int d = i & 63;
        int g = slot / 6, m = slot - g * 6;
        float v1 = (float)src[slot * 128 + d];
        float v2 = (float)src[slot * 128 + d + 64];
        float o1, o2;
        if (m < 5) {
            float c1 = cosb[t * 128 + d],      s1 = sinb[t * 128 + d];
            float c2 = cosb[t * 128 + d + 64], s2 = sinb[t * 128 + d + 64];
            o1 = v1 * c1 - v2 * s1;
            o2 = v2 * c2 + v1 * s2;
        } else {
            o1 = v1; o2 = v2;
        }
        if (m < 4) {
            int hh = g * 4 + m;
            size_t base = ((size_t)(b * 16 + hh) * 2048 + t) * 128;
            Q[base + d] = (bf16)o1;
            Q[base + d + 64] = (bf16)o2;
        } else if (m == 4) {
            size_t base = ((size_t)(b * 4 + g) * 2048 + t) * 128;
            Kg[base + d] = (bf16)o1;
            Kg[base + d + 64] = (bf16)o2;
        } else {
            size_t base = (size_t)(b * 4 + g) * 128;
            Vt[(base + d) * 2048 + t] = (bf16)o1;
            Vt[(base + d + 64) * 2048 + t] = (bf16)o2;
        }
    }
}

// ---------------------------------------------------------------- causal flash attention
// Q (B,16,T,128), K (B,4,T,128), Vt (B,4,128,T)  ->  Y (B,T,16*128) bf16
__global__ __launch_bounds__(256) void attn_kernel(const bf16* __restrict__ Q,
                                                   const bf16* __restrict__ Kg,
                                                   const bf16* __restrict__ Vt,
                                                   bf16* __restrict__ Y) {
    __shared__ __align__(16) bf16 Ks[64 * 128];       // swizzled [t][d]
    __shared__ __align__(16) bf16 Vs[128 * 64];       // swizzled [d][t]
    __shared__ __align__(16) bf16 Ps[4][16 * 80];     // per-wave P [q][t] pad 80

    const int tid = threadIdx.x;
    const int lane = tid & 63, w = tid >> 6;
    const int lo = lane & 15, hi = lane >> 4;
    const int q0 = blockIdx.x * 64;
    const int bh = blockIdx.y;
    const int b = bh >> 4, h = bh & 15;
    const int g = h >> 2;

    // Q fragments (A operand), rows = q0 + w*16 + lo
    bf16x8 qf[4];
    {
        const size_t qbase = ((size_t)bh * 2048 + q0 + w * 16 + lo) * 128;
        #pragma unroll
        for (int dd = 0; dd < 4; ++dd)
            qf[dd] = *(const bf16x8*)(Q + qbase + dd * 32 + hi * 8);
    }
    const bf16* Kbase = Kg + (size_t)(b * 4 + g) * 2048 * 128;
    const bf16* Vbase = Vt + (size_t)(b * 4 + g) * 128 * 2048;

    float m_r[4], l_r[4];
    f32x4 oacc[8] = {};
    #pragma unroll
    for (int r = 0; r < 4; ++r) { m_r[r] = -1e30f; l_r[r] = 0.f; }

    const int ktlast = blockIdx.x;
    const float scale = 0.08838834764831845f;   // 1/sqrt(128)
    bf16* pw = &Ps[w][0];

    for (int kt = 0; kt <= ktlast; ++kt) {
        // ---- stage K (64x128) and V^T (128x64), XOR-swizzled
        #pragma unroll
        for (int it = 0; it < 4; ++it) {
            int ob = (it * 256 + tid) * 16;
            int r  = ob >> 8, cb = ob & 255;
            bf16x8 kv = *(const bf16x8*)(Kbase + (size_t)(kt * 64 + r) * 128 + (cb >> 1));
            *(bf16x8*)((char*)Ks + r * 256 + (cb ^ ((r & 7) << 4))) = kv;
            int dv = ob >> 7, cv = ob & 127;
            bf16x8 vv = *(const bf16x8*)(Vbase + (size_t)dv * 2048 + kt * 64 + (cv >> 1));
            *(bf16x8*)((char*)Vs + dv * 128 + (cv ^ ((dv & 7) << 4))) = vv;
        }
        __syncthreads();

        // ---- S = Q K^T : 4 t-subtiles of 16
        f32x4 sj[4];
        #pragma unroll
        for (int j = 0; j < 4; ++j) {
            f32x4 a = {};
            int r = j * 16 + lo;
            #pragma unroll
            for (int dd = 0; dd < 4; ++dd) {
                int cb = dd * 64 + hi * 16;
                bf16x8 kf = *(const bf16x8*)((const char*)Ks + r * 256 + (cb ^ ((r & 7) << 4)));
                a = __builtin_amdgcn_mfma_f32_16x16x32_bf16(qf[dd], kf, a, 0, 0, 0);
            }
            sj[j] = a;
        }

        // ---- scale + causal mask
        float sv[4][4];
        const bool diag = (kt == ktlast);
        #pragma unroll
        for (int j = 0; j < 4; ++j)
            #pragma unroll
            for (int rr = 0; rr < 4; ++rr) {
                float v = sj[j][rr] * scale;
                if (diag) {
                    int tg = kt * 64 + j * 16 + lo;
                    int qg = q0 + w * 16 + hi * 4 + rr;
                    if (tg > qg) v = -1e30f;
                }
                sv[j][rr] = v;
            }

        // ---- online softmax (rows live across lanes lo=0..15 of same hi group)
        float mx[4];
        #pragma unroll
        for (int rr = 0; rr < 4; ++rr) {
            float m0 = fmaxf(fmaxf(sv[0][rr], sv[1][rr]), fmaxf(sv[2][rr], sv[3][rr]));
            #pragma unroll
            for (int off = 8; off; off >>= 1) m0 = fmaxf(m0, __shfl_xor(m0, off, 16));
            mx[rr] = m0;
        }
        float p[4][4];
        float rs[4], al[4];
        #pragma unroll
        for (int rr = 0; rr < 4; ++rr) {
            float mnew = fmaxf(m_r[rr], mx[rr]);
            #pragma unroll
            for (int j = 0; j < 4; ++j)
                p[j][rr] = exp2f((sv[j][rr] - mnew) * LOG2E);
            float s0 = p[0][rr] + p[1][rr] + p[2][rr] + p[3][rr];
            #pragma unroll
            for (int off = 8; off; off >>= 1) s0 += __shfl_xor(s0, off, 16);
            rs[rr] = s0;
            al[rr] = exp2f((m_r[rr] - mnew) * LOG2E);
            l_r[rr] = l_r[rr] * al[rr] + rs[rr];
            m_r[rr] = mnew;
        }
        #pragma unroll
        for (int dn = 0; dn < 8; ++dn)
            #pragma unroll
            for (int rr = 0; rr < 4; ++rr) oacc[dn][rr] *= al[rr];

        // ---- write P to per-wave LDS [16 q][80 t]
        #pragma unroll
        for (int j = 0; j < 4; ++j)
            #pragma unroll
            for (int rr = 0; rr < 4; ++rr)
                pw[(hi * 4 + rr) * 80 + j * 16 + lo] = (bf16)p[j][rr];

        // ---- O += P V
        #pragma unroll
        for (int tc = 0; tc < 2; ++tc) {
            bf16x8 pf = *(const bf16x8*)(pw + lo * 80 + tc * 32 + hi * 8);
            #pragma unroll
            for (int dn = 0; dn < 8; ++dn) {
                int rv = dn * 16 + lo;
                int cv = tc * 64 + hi * 16;
                bf16x8 vf = *(const bf16x8*)((const char*)Vs + rv * 128 + (cv ^ ((rv & 7) << 4)));
                oacc[dn] = __builtin_amdgcn_mfma_f32_16x16x32_bf16(pf, vf, oacc[dn], 0, 0, 0);
            }
        }
        __syncthreads();
    }

    // ---- epilogue: Y[(b, q, h*128 + d)] = O / l
    #pragma unroll
    for (int dn = 0; dn < 8; ++dn)
        #pragma unroll
        for (int rr = 0; rr < 4; ++rr) {
            int qg = q0 + w * 16 + hi * 4 + rr;
            Y[((size_t)b * 2048 + qg) * 2048 + h * 128 + dn * 16 + lo] =
                (bf16)(oacc[dn][rr] / l_r[rr]);
        }
}

// ---------------------------------------------------------------- launch
extern "C" void kernel_launch(void* const* d_in, const int* in_sizes, int n_in,
                              void* d_out, int out_size, void* d_ws, size_t ws_size,
                              hipStream_t stream) {
    const float* x      = (const float*)d_in[0];
    const float* cosb   = (const float*)d_in[1];
    const float* sinb   = (const float*)d_in[2];
    const float* ln1_w  = (const float*)d_in[4];
    const float* ln1_b  = (const float*)d_in[5];
    const float* qkv_w  = (const float*)d_in[6];
    const float* proj_w = (const float*)d_in[7];
    const float* ln2_w  = (const float*)d_in[8];
    const float* ln2_b  = (const float*)d_in[9];
    const float* fc1_w  = (const float*)d_in[10];
    const float* fc1_b  = (const float*)d_in[11];
    const float* fc2_w  = (const float*)d_in[12];
    const float* fc2_b  = (const float*)d_in[13];
    float* out = (float*)d_out;

    char* ws = (char*)d_ws;
    bf16*  w_qkv  = (bf16*)(ws + 0ull);            // 3072x2048
    bf16*  w_proj = (bf16*)(ws + 12582912ull);     // 2048x2048
    bf16*  w_fc1  = (bf16*)(ws + 20971520ull);     // 8192x2048
    bf16*  w_fc2  = (bf16*)(ws + 54525952ull);     // 2048x8192
    float* x2     = (float*)(ws + 88080384ull);    // 4096x2048 f32
    bf16*  lnout  = (bf16*)(ws + 121634816ull);    // 4096x2048
    char*  R      = ws + 138412032ull;             // aliased region (67.1 MB)
    bf16*  qkvo = (bf16*)(R);                      // 4096x3072
    bf16*  Qb   = (bf16*)(R + 25165824ull);        // 2,16,2048,128
    bf16*  Kb   = (bf16*)(R + 41943040ull);        // 2,4,2048,128
    bf16*  Vtb  = (bf16*)(R + 46137344ull);        // 2,4,128,2048
    bf16*  Yb   = (bf16*)(R + 50331648ull);        // 4096x2048
    bf16*  mlp  = (bf16*)(R);                      // 4096x8192 (aliases all above)

    cvt_bf16<<<6144,  256, 0, stream>>>(qkv_w,  w_qkv,  3072 * 2048);
    cvt_bf16<<<4096,  256, 0, stream>>>(proj_w, w_proj, 2048 * 2048);
    cvt_bf16<<<16384, 256, 0, stream>>>(fc1_w,  w_fc1,  8192 * 2048);
    cvt_bf16<<<16384, 256, 0, stream>>>(fc2_w,  w_fc2,  2048 * 8192);

    ln_kernel<<<4096, 256, 0, stream>>>(x, ln1_w, ln1_b, lnout);

    gemm_bt<0><<<dim3(24, 32), 256, 0, stream>>>(lnout, w_qkv, qkvo, nullptr, nullptr,
                                                 4096, 3072, 2048);

    rope_scatter<<<4096, 256, 0, stream>>>(qkvo, cosb, sinb, Qb, Kb, Vtb);

    attn_kernel<<<dim3(32, 32), 256, 0, stream>>>(Qb, Kb, Vtb, Yb);

    gemm_bt<2><<<dim3(16, 32), 256, 0, stream>>>(Yb, w_proj, x2, nullptr, x,
                                                 4096, 2048, 2048);

    ln_kernel<<<4096, 256, 0, stream>>>(x2, ln2_w, ln2_b, lnout);

    gemm_bt<1><<<dim3(64, 32), 256, 0, stream>>>(lnout, w_fc1, mlp, fc1_b, nullptr,
                                                 4096, 8192, 2048);

    gemm_bt<3><<<dim3(16, 32), 256, 0, stream>>>(mlp, w_fc2, out, fc2_b, x2,
                                                 4096, 2048, 8192);
}

// Round 2
// 810.685 us; speedup vs baseline: 1.0334x; 1.0334x over previous
//
#include <hip/hip_runtime.h>

typedef __bf16 bf16;
typedef __bf16 bf16x8 __attribute__((ext_vector_type(8)));
typedef __bf16 bf16x4 __attribute__((ext_vector_type(4)));
typedef float  f32x4  __attribute__((ext_vector_type(4)));

#define LOG2E 1.4426950408889634f

// ---------------------------------------------------------------- helpers
__device__ __forceinline__ void gload_lds16(const void* g, void* l) {
    __builtin_amdgcn_global_load_lds(
        (__attribute__((address_space(1))) const void*)g,
        (__attribute__((address_space(3))) void*)l, 16, 0, 0);
}

// ---------------------------------------------------------------- f32 -> bf16 weight convert
__global__ __launch_bounds__(256) void cvt_bf16(const float* __restrict__ src,
                                                bf16* __restrict__ dst, int n) {
    int i = (blockIdx.x * 256 + threadIdx.x) * 4;
    if (i + 3 < n) {
        float4 v = *(const float4*)(src + i);
        bf16x4 o;
        o[0] = (bf16)v.x; o[1] = (bf16)v.y; o[2] = (bf16)v.z; o[3] = (bf16)v.w;
        *(bf16x4*)(dst + i) = o;
    }
}

// ---------------------------------------------------------------- LayerNorm (f32 in, bf16 out), row = 2048
__global__ __launch_bounds__(256) void ln_kernel(const float* __restrict__ x,
                                                 const float* __restrict__ wgt,
                                                 const float* __restrict__ bias,
                                                 bf16* __restrict__ out) {
    __shared__ float red[8];
    const int tid = threadIdx.x;
    const int lane = tid & 63, w = tid >> 6;
    const size_t row = blockIdx.x;
    const float4* xr = (const float4*)(x + row * 2048);
    float4 v0 = xr[tid];
    float4 v1 = xr[tid + 256];
    float s = v0.x + v0.y + v0.z + v0.w + v1.x + v1.y + v1.z + v1.w;
    float q = v0.x*v0.x + v0.y*v0.y + v0.z*v0.z + v0.w*v0.w
            + v1.x*v1.x + v1.y*v1.y + v1.z*v1.z + v1.w*v1.w;
    #pragma unroll
    for (int off = 32; off; off >>= 1) {
        s += __shfl_xor(s, off);
        q += __shfl_xor(q, off);
    }
    if (lane == 0) { red[w] = s; red[4 + w] = q; }
    __syncthreads();
    float S  = red[0] + red[1] + red[2] + red[3];
    float Q2 = red[4] + red[5] + red[6] + red[7];
    float mu = S * (1.0f / 2048.0f);
    float var = Q2 * (1.0f / 2048.0f) - mu * mu;
    float rstd = rsqrtf(var + 1e-5f);

    bf16* orow = out + row * 2048;
    int c0 = tid * 4;
    float vv[8] = {v0.x, v0.y, v0.z, v0.w, v1.x, v1.y, v1.z, v1.w};
    bf16x4 o;
    #pragma unroll
    for (int k = 0; k < 4; ++k)
        o[k] = (bf16)((vv[k] - mu) * rstd * wgt[c0 + k] + bias[c0 + k]);
    *(bf16x4*)(orow + c0) = o;
    #pragma unroll
    for (int k = 0; k < 4; ++k)
        o[k] = (bf16)((vv[4 + k] - mu) * rstd * wgt[1024 + c0 + k] + bias[1024 + c0 + k]);
    *(bf16x4*)(orow + 1024 + c0) = o;
}

// ---------------------------------------------------------------- GEMM  C[M,N] = A[M,K] * B[N,K]^T  (both bf16)
// BM x 256 tile, BK=64, 8 waves (2 x 4), 512 threads, double-buffered LDS,
// counted vmcnt, raw barriers, XCD-bijective swizzle + column-supertile order.
// EPI: 0 = bf16 out, 1 = +bias, exact GELU, bf16 out, 2 = res + acc -> f32, 3 = res + acc + bias -> f32
template <int BM, int EPI>
__global__ __launch_bounds__(512, 2) void gemm2(const bf16* __restrict__ A,
                                                const bf16* __restrict__ B,
                                                void* __restrict__ OutP,
                                                const float* __restrict__ bias,
                                                const float* __restrict__ res,
                                                int M, int N, int K) {
    constexpr int A_SZ = BM * 128;        // bytes of A tile (BM x 64 bf16)
    constexpr int B_SZ = 32768;           // 256 x 64 bf16
    constexpr int BUF  = A_SZ + B_SZ;
    constexpr int AISS = BM / 64;         // gload issues for A per tile
    constexpr int LPS  = AISS + 4;        // loads per stage per thread
    constexpr int MFR  = BM / 32;         // m-fragments per wave
    __shared__ __align__(16) char lds[2 * BUF];

    const int tid = threadIdx.x;
    const int lane = tid & 63;
    const int w = tid >> 6, wr = w >> 2, wc = w & 3;
    const int lo = lane & 15, hi = lane >> 4;

    // ---- block swizzle: XCD-bijective, then column-groups of 4 (M-major inside)
    const int nwg = gridDim.x;
    const int bid = blockIdx.x;
    const int q = nwg >> 3, r = nwg & 7, xcd = bid & 7, off = bid >> 3;
    const int s = (xcd < r ? xcd * (q + 1) : r * (q + 1) + (xcd - r) * q) + off;
    const int MB = M / BM;
    const int per = MB * 4;
    const int grp = s / per, t2 = s - grp * per;
    const int brow = (t2 % MB) * BM;
    const int bcol = (grp * 4 + t2 / MB) * 256;

    // ---- staging addresses
    const int sr = tid >> 3;
    const int sc = (tid & 7) * 8;
    const bf16* Ag = A + (size_t)(brow + sr) * K + sc;
    const bf16* Bg = B + (size_t)(bcol + sr) * K + sc;

    f32x4 acc[MFR][4] = {};

    auto stage = [&](int buf, int kt) {
        char* al = lds + buf * BUF + tid * 16;
        #pragma unroll
        for (int it = 0; it < AISS; ++it)
            gload_lds16(Ag + (size_t)(it * 64) * K + kt * 64, al + it * 8192);
        char* bl = lds + buf * BUF + A_SZ + tid * 16;
        #pragma unroll
        for (int it = 0; it < 4; ++it)
            gload_lds16(Bg + (size_t)(it * 64) * K + kt * 64, bl + it * 8192);
    };

    const int NT = K >> 6;
    stage(0, 0);
    for (int t = 0; t < NT; ++t) {
        const int buf = t & 1;
        const bool pf = (t + 1 < NT);
        if (pf) {
            stage(buf ^ 1, t + 1);
            if constexpr (BM == 256) asm volatile("s_waitcnt vmcnt(8)" ::: "memory");
            else                     asm volatile("s_waitcnt vmcnt(6)" ::: "memory");
        } else {
            asm volatile("s_waitcnt vmcnt(0)" ::: "memory");
        }
        __builtin_amdgcn_s_barrier();

        const char* ab = lds + buf * BUF + (wr * (BM / 2) + lo) * 128 + hi * 16;
        const char* bb = lds + buf * BUF + A_SZ + (wc * 64 + lo) * 128 + hi * 16;
        #pragma unroll
        for (int ks = 0; ks < 2; ++ks) {
            bf16x8 af[MFR], bfv[4];
            #pragma unroll
            for (int m = 0; m < MFR; ++m) af[m] = *(const bf16x8*)(ab + m * 2048 + ks * 64);
            #pragma unroll
            for (int n = 0; n < 4; ++n) bfv[n] = *(const bf16x8*)(bb + n * 2048 + ks * 64);
            #pragma unroll
            for (int m = 0; m < MFR; ++m)
                #pragma unroll
                for (int n = 0; n < 4; ++n)
                    acc[m][n] = __builtin_amdgcn_mfma_f32_16x16x32_bf16(af[m], bfv[n], acc[m][n], 0, 0, 0);
        }
        __builtin_amdgcn_s_barrier();
    }

    // ---- epilogue
    float* outF = (float*)OutP;
    bf16*  outB = (bf16*)OutP;
    #pragma unroll
    for (int n = 0; n < 4; ++n) {
        const int col = bcol + wc * 64 + n * 16 + lo;
        float bv = 0.f;
        if (EPI == 1 || EPI == 3) bv = bias[col];
        #pragma unroll
        for (int m = 0; m < MFR; ++m) {
            #pragma unroll
            for (int rr = 0; rr < 4; ++rr) {
                const int row = brow + wr * (BM / 2) + m * 16 + hi * 4 + rr;
                float v = acc[m][n][rr];
                if (EPI == 0) {
                    outB[(size_t)row * N + col] = (bf16)v;
                } else if (EPI == 1) {
                    v += bv;
                    v = 0.5f * v * (1.0f + erff(v * 0.70710678118654752f));
                    outB[(size_t)row * N + col] = (bf16)v;
                } else if (EPI == 2) {
                    outF[(size_t)row * N + col] = res[(size_t)row * N + col] + v;
                } else {
                    outF[(size_t)row * N + col] = res[(size_t)row * N + col] + v + bv;
                }
            }
        }
    }
}

// ---------------------------------------------------------------- RoPE + GQA scatter
// qkv: (B*T, 3072) bf16  ->  Q (B,16,T,128), K (B,4,T,128), Vt (B,4,128,T)
__global__ __launch_bounds__(256) void rope_scatter(const bf16* __restrict__ qkv,
                                                    const float* __restrict__ cosb,
                                                    const float* __restrict__ sinb,
                                                    bf16* __restrict__ Q,
                                                    bf16* __restrict__ Kg,
                                                    bf16* __restrict__ Vt) {
    const int tid = threadIdx.x;
    const int row = blockIdx.x;          // b*T + t
    const int b = row >> 11, t = row & 2047;
    const bf16* src = qkv + (size_t)row * 3072;
    for (int i = tid; i < 1536; i += 256) {
        int slot = i >> 6;               // 0..23  = g*6 + m
        int d = i & 63;
        int g = slot / 6, m = slot - g * 6;
        float v1 = (float)src[slot * 128 + d];
        float v2 = (float)src[slot * 128 + d + 64];
        float o1, o2;
        if (m < 5) {
            float c1 = cosb[t * 128 + d],      s1 = sinb[t * 128 + d];
            float c2 = cosb[t * 128 + d + 64], s2 = sinb[t * 128 + d + 64];
            o1 = v1 * c1 - v2 * s1;
            o2 = v2 * c2 + v1 * s2;
        } else {
            o1 = v1; o2 = v2;
        }
        if (m < 4) {
            int hh = g * 4 + m;
            size_t base = ((size_t)(b * 16 + hh) * 2048 + t) * 128;
            Q[base + d] = (bf16)o1;
            Q[base + d + 64] = (bf16)o2;
        } else if (m == 4) {
            size_t base = ((size_t)(b * 4 + g) * 2048 + t) * 128;
            Kg[base + d] = (bf16)o1;
            Kg[base + d + 64] = (bf16)o2;
        } else {
            size_t base = (size_t)(b * 4 + g) * 128;
            Vt[(base + d) * 2048 + t] = (bf16)o1;
            Vt[(base + d + 64) * 2048 + t] = (bf16)o2;
        }
    }
}

// ---------------------------------------------------------------- causal flash attention
// Q (B,16,T,128), K (B,4,T,128), Vt (B,4,128,T)  ->  Y (B,T,16*128) bf16
__global__ __launch_bounds__(256) void attn_kernel(const bf16* __restrict__ Q,
                                                   const bf16* __restrict__ Kg,
                                                   const bf16* __restrict__ Vt,
                                                   bf16* __restrict__ Y) {
    __shared__ __align__(16) bf16 Ks[64 * 128];       // swizzled [t][d]
    __shared__ __align__(16) bf16 Vs[128 * 64];       // swizzled [d][t]
    __shared__ __align__(16) bf16 Ps[4][16 * 80];     // per-wave P [q][t] pad 80

    const int tid = threadIdx.x;
    const int lane = tid & 63, w = tid >> 6;
    const int lo = lane & 15, hi = lane >> 4;
    const int q0 = blockIdx.x * 64;
    const int bh = blockIdx.y;
    const int b = bh >> 4, h = bh & 15;
    const int g = h >> 2;

    // Q fragments (A operand), rows = q0 + w*16 + lo
    bf16x8 qf[4];
    {
        const size_t qbase = ((size_t)bh * 2048 + q0 + w * 16 + lo) * 128;
        #pragma unroll
        for (int dd = 0; dd < 4; ++dd)
            qf[dd] = *(const bf16x8*)(Q + qbase + dd * 32 + hi * 8);
    }
    const bf16* Kbase = Kg + (size_t)(b * 4 + g) * 2048 * 128;
    const bf16* Vbase = Vt + (size_t)(b * 4 + g) * 128 * 2048;

    float m_r[4], l_r[4];
    f32x4 oacc[8] = {};
    #pragma unroll
    for (int r = 0; r < 4; ++r) { m_r[r] = -1e30f; l_r[r] = 0.f; }

    const int ktlast = blockIdx.x;
    const float scale = 0.08838834764831845f;   // 1/sqrt(128)
    bf16* pw = &Ps[w][0];

    for (int kt = 0; kt <= ktlast; ++kt) {
        // ---- stage K (64x128) and V^T (128x64), XOR-swizzled
        #pragma unroll
        for (int it = 0; it < 4; ++it) {
            int ob = (it * 256 + tid) * 16;
            int r  = ob >> 8, cb = ob & 255;
            bf16x8 kv = *(const bf16x8*)(Kbase + (size_t)(kt * 64 + r) * 128 + (cb >> 1));
            *(bf16x8*)((char*)Ks + r * 256 + (cb ^ ((r & 7) << 4))) = kv;
            int dv = ob >> 7, cv = ob & 127;
            bf16x8 vv = *(const bf16x8*)(Vbase + (size_t)dv * 2048 + kt * 64 + (cv >> 1));
            *(bf16x8*)((char*)Vs + dv * 128 + (cv ^ ((dv & 7) << 4))) = vv;
        }
        __syncthreads();

        // ---- S = Q K^T : 4 t-subtiles of 16
        f32x4 sj[4];
        #pragma unroll
        for (int j = 0; j < 4; ++j) {
            f32x4 a = {};
            int r = j * 16 + lo;
            #pragma unroll
            for (int dd = 0; dd < 4; ++dd) {
                int cb = dd * 64 + hi * 16;
                bf16x8 kf = *(const bf16x8*)((const char*)Ks + r * 256 + (cb ^ ((r & 7) << 4)));
                a = __builtin_amdgcn_mfma_f32_16x16x32_bf16(qf[dd], kf, a, 0, 0, 0);
            }
            sj[j] = a;
        }

        // ---- scale + causal mask
        float sv[4][4];
        const bool diag = (kt == ktlast);
        #pragma unroll
        for (int j = 0; j < 4; ++j)
            #pragma unroll
            for (int rr = 0; rr < 4; ++rr) {
                float v = sj[j][rr] * scale;
                if (diag) {
                    int tg = kt * 64 + j * 16 + lo;
                    int qg = q0 + w * 16 + hi * 4 + rr;
                    if (tg > qg) v = -1e30f;
                }
                sv[j][rr] = v;
            }

        // ---- online softmax (rows live across lanes lo=0..15 of same hi group)
        float mx[4];
        #pragma unroll
        for (int rr = 0; rr < 4; ++rr) {
            float m0 = fmaxf(fmaxf(sv[0][rr], sv[1][rr]), fmaxf(sv[2][rr], sv[3][rr]));
            #pragma unroll
            for (int off = 8; off; off >>= 1) m0 = fmaxf(m0, __shfl_xor(m0, off, 16));
            mx[rr] = m0;
        }
        float p[4][4];
        float rs[4], al[4];
        #pragma unroll
        for (int rr = 0; rr < 4; ++rr) {
            float mnew = fmaxf(m_r[rr], mx[rr]);
            #pragma unroll
            for (int j = 0; j < 4; ++j)
                p[j][rr] = exp2f((sv[j][rr] - mnew) * LOG2E);
            float s0 = p[0][rr] + p[1][rr] + p[2][rr] + p[3][rr];
            #pragma unroll
            for (int off = 8; off; off >>= 1) s0 += __shfl_xor(s0, off, 16);
            rs[rr] = s0;
            al[rr] = exp2f((m_r[rr] - mnew) * LOG2E);
            l_r[rr] = l_r[rr] * al[rr] + rs[rr];
            m_r[rr] = mnew;
        }
        #pragma unroll
        for (int dn = 0; dn < 8; ++dn)
            #pragma unroll
            for (int rr = 0; rr < 4; ++rr) oacc[dn][rr] *= al[rr];

        // ---- write P to per-wave LDS [16 q][80 t]
        #pragma unroll
        for (int j = 0; j < 4; ++j)
            #pragma unroll
            for (int rr = 0; rr < 4; ++rr)
                pw[(hi * 4 + rr) * 80 + j * 16 + lo] = (bf16)p[j][rr];

        // ---- O += P V
        #pragma unroll
        for (int tc = 0; tc < 2; ++tc) {
            bf16x8 pf = *(const bf16x8*)(pw + lo * 80 + tc * 32 + hi * 8);
            #pragma unroll
            for (int dn = 0; dn < 8; ++dn) {
                int rv = dn * 16 + lo;
                int cv = tc * 64 + hi * 16;
                bf16x8 vf = *(const bf16x8*)((const char*)Vs + rv * 128 + (cv ^ ((rv & 7) << 4)));
                oacc[dn] = __builtin_amdgcn_mfma_f32_16x16x32_bf16(pf, vf, oacc[dn], 0, 0, 0);
            }
        }
        __syncthreads();
    }

    // ---- epilogue: Y[(b, q, h*128 + d)] = O / l
    #pragma unroll
    for (int dn = 0; dn < 8; ++dn)
        #pragma unroll
        for (int rr = 0; rr < 4; ++rr) {
            int qg = q0 + w * 16 + hi * 4 + rr;
            Y[((size_t)b * 2048 + qg) * 2048 + h * 128 + dn * 16 + lo] =
                (bf16)(oacc[dn][rr] / l_r[rr]);
        }
}

// ---------------------------------------------------------------- launch
extern "C" void kernel_launch(void* const* d_in, const int* in_sizes, int n_in,
                              void* d_out, int out_size, void* d_ws, size_t ws_size,
                              hipStream_t stream) {
    const float* x      = (const float*)d_in[0];
    const float* cosb   = (const float*)d_in[1];
    const float* sinb   = (const float*)d_in[2];
    const float* ln1_w  = (const float*)d_in[4];
    const float* ln1_b  = (const float*)d_in[5];
    const float* qkv_w  = (const float*)d_in[6];
    const float* proj_w = (const float*)d_in[7];
    const float* ln2_w  = (const float*)d_in[8];
    const float* ln2_b  = (const float*)d_in[9];
    const float* fc1_w  = (const float*)d_in[10];
    const float* fc1_b  = (const float*)d_in[11];
    const float* fc2_w  = (const float*)d_in[12];
    const float* fc2_b  = (const float*)d_in[13];
    float* out = (float*)d_out;

    char* ws = (char*)d_ws;
    bf16*  w_qkv  = (bf16*)(ws + 0ull);            // 3072x2048
    bf16*  w_proj = (bf16*)(ws + 12582912ull);     // 2048x2048
    bf16*  w_fc1  = (bf16*)(ws + 20971520ull);     // 8192x2048
    bf16*  w_fc2  = (bf16*)(ws + 54525952ull);     // 2048x8192
    float* x2     = (float*)(ws + 88080384ull);    // 4096x2048 f32
    bf16*  lnout  = (bf16*)(ws + 121634816ull);    // 4096x2048
    char*  R      = ws + 138412032ull;             // aliased region (67.1 MB)
    bf16*  qkvo = (bf16*)(R);                      // 4096x3072
    bf16*  Qb   = (bf16*)(R + 25165824ull);        // 2,16,2048,128
    bf16*  Kb   = (bf16*)(R + 41943040ull);        // 2,4,2048,128
    bf16*  Vtb  = (bf16*)(R + 46137344ull);        // 2,4,128,2048
    bf16*  Yb   = (bf16*)(R + 50331648ull);        // 4096x2048
    bf16*  mlp  = (bf16*)(R);                      // 4096x8192 (aliases all above)

    cvt_bf16<<<6144,  256, 0, stream>>>(qkv_w,  w_qkv,  3072 * 2048);
    cvt_bf16<<<4096,  256, 0, stream>>>(proj_w, w_proj, 2048 * 2048);
    cvt_bf16<<<16384, 256, 0, stream>>>(fc1_w,  w_fc1,  8192 * 2048);
    cvt_bf16<<<16384, 256, 0, stream>>>(fc2_w,  w_fc2,  2048 * 8192);

    ln_kernel<<<4096, 256, 0, stream>>>(x, ln1_w, ln1_b, lnout);

    gemm2<256, 0><<<192, 512, 0, stream>>>(lnout, w_qkv, qkvo, nullptr, nullptr,
                                           4096, 3072, 2048);

    rope_scatter<<<4096, 256, 0, stream>>>(qkvo, cosb, sinb, Qb, Kb, Vtb);

    attn_kernel<<<dim3(32, 32), 256, 0, stream>>>(Qb, Kb, Vtb, Yb);

    gemm2<128, 2><<<256, 512, 0, stream>>>(Yb, w_proj, x2, nullptr, x,
                                           4096, 2048, 2048);

    ln_kernel<<<4096, 256, 0, stream>>>(x2, ln2_w, ln2_b, lnout);

    gemm2<256, 1><<<512, 512, 0, stream>>>(lnout, w_fc1, mlp, fc1_b, nullptr,
                                           4096, 8192, 2048);

    gemm2<128, 3><<<256, 512, 0, stream>>>(mlp, w_fc2, out, fc2_b, x2,
                                           4096, 2048, 8192);
}

// Round 3
// 788.096 us; speedup vs baseline: 1.0631x; 1.0287x over previous
//
#include <hip/hip_runtime.h>

typedef __bf16 bf16;
typedef __bf16 bf16x8 __attribute__((ext_vector_type(8)));
typedef __bf16 bf16x4 __attribute__((ext_vector_type(4)));
typedef float  f32x4  __attribute__((ext_vector_type(4)));

#define LOG2E 1.4426950408889634f

// ---------------------------------------------------------------- helpers
__device__ __forceinline__ void gload_lds16(const void* g, void* l) {
    __builtin_amdgcn_global_load_lds(
        (__attribute__((address_space(1))) const void*)g,
        (__attribute__((address_space(3))) void*)l, 16, 0, 0);
}

// ---------------------------------------------------------------- f32 -> bf16 weight convert
__global__ __launch_bounds__(256) void cvt_bf16(const float* __restrict__ src,
                                                bf16* __restrict__ dst, int n) {
    int i = (blockIdx.x * 256 + threadIdx.x) * 4;
    if (i + 3 < n) {
        float4 v = *(const float4*)(src + i);
        bf16x4 o;
        o[0] = (bf16)v.x; o[1] = (bf16)v.y; o[2] = (bf16)v.z; o[3] = (bf16)v.w;
        *(bf16x4*)(dst + i) = o;
    }
}

// ---------------------------------------------------------------- LayerNorm (f32 in, bf16 out), row = 2048
__global__ __launch_bounds__(256) void ln_kernel(const float* __restrict__ x,
                                                 const float* __restrict__ wgt,
                                                 const float* __restrict__ bias,
                                                 bf16* __restrict__ out) {
    __shared__ float red[8];
    const int tid = threadIdx.x;
    const int lane = tid & 63, w = tid >> 6;
    const size_t row = blockIdx.x;
    const float4* xr = (const float4*)(x + row * 2048);
    float4 v0 = xr[tid];
    float4 v1 = xr[tid + 256];
    float s = v0.x + v0.y + v0.z + v0.w + v1.x + v1.y + v1.z + v1.w;
    float q = v0.x*v0.x + v0.y*v0.y + v0.z*v0.z + v0.w*v0.w
            + v1.x*v1.x + v1.y*v1.y + v1.z*v1.z + v1.w*v1.w;
    #pragma unroll
    for (int off = 32; off; off >>= 1) {
        s += __shfl_xor(s, off);
        q += __shfl_xor(q, off);
    }
    if (lane == 0) { red[w] = s; red[4 + w] = q; }
    __syncthreads();
    float S  = red[0] + red[1] + red[2] + red[3];
    float Q2 = red[4] + red[5] + red[6] + red[7];
    float mu = S * (1.0f / 2048.0f);
    float var = Q2 * (1.0f / 2048.0f) - mu * mu;
    float rstd = rsqrtf(var + 1e-5f);

    bf16* orow = out + row * 2048;
    int c0 = tid * 4;
    float vv[8] = {v0.x, v0.y, v0.z, v0.w, v1.x, v1.y, v1.z, v1.w};
    bf16x4 o;
    #pragma unroll
    for (int k = 0; k < 4; ++k)
        o[k] = (bf16)((vv[k] - mu) * rstd * wgt[c0 + k] + bias[c0 + k]);
    *(bf16x4*)(orow + c0) = o;
    #pragma unroll
    for (int k = 0; k < 4; ++k)
        o[k] = (bf16)((vv[4 + k] - mu) * rstd * wgt[1024 + c0 + k] + bias[1024 + c0 + k]);
    *(bf16x4*)(orow + 1024 + c0) = o;
}

// ---------------------------------------------------------------- GEMM  C[M,N] = A[M,K] * B[N,K]^T  (both bf16)
// BM x 256 tile, BK=32, 8 waves (2 x 4), 512 threads, TRIPLE-buffered LDS,
// stages issued 2 K-tiles ahead, counted vmcnt (never 0 in steady state),
// conflict-free 64B-row LDS layout, XCD-bijective swizzle + column supertiles.
// EPI: 0 = bf16 out, 1 = +bias exact GELU bf16 out, 2 = res+acc->f32, 3 = res+acc+bias->f32
template <int BM, int EPI>
__global__ __launch_bounds__(512, 2) void gemm3(const bf16* __restrict__ A,
                                                const bf16* __restrict__ B,
                                                void* __restrict__ OutP,
                                                const float* __restrict__ bias,
                                                const float* __restrict__ res,
                                                int M, int N, int K) {
    constexpr int A_SZ = BM * 64;          // bytes: BM rows x 32 bf16
    constexpr int B_SZ = 256 * 64;         // 256 rows x 32 bf16
    constexpr int BUF  = A_SZ + B_SZ;
    constexpr int AISS = BM / 128;         // 8KB gload issues for A (1 or 2)
    constexpr int MFR  = BM / 32;          // m-fragments per wave
    extern __shared__ __align__(16) char lds[];

    const int tid = threadIdx.x;
    const int lane = tid & 63;
    const int w = tid >> 6, wr = w >> 2, wc = w & 3;
    const int lo = lane & 15, hi = lane >> 4;

    // ---- block swizzle: XCD-bijective, then column-groups of 4 (M-major inside)
    const int nwg = gridDim.x;
    const int bid = blockIdx.x;
    const int q = nwg >> 3, r = nwg & 7, xcd = bid & 7, off = bid >> 3;
    const int s = (xcd < r ? xcd * (q + 1) : r * (q + 1) + (xcd - r) * q) + off;
    const int MB = M / BM;
    const int per = MB * 4;
    const int grp = s / per, t2 = s - grp * per;
    const int brow = (t2 % MB) * BM;
    const int bcol = (grp * 4 + t2 / MB) * 256;

    // ---- staging addresses: 4 threads per row, 16B each (BK=32 -> 64B rows)
    const int sr = tid >> 2;
    const int sc = (tid & 3) * 8;
    const bf16* Ag = A + (size_t)(brow + sr) * K + sc;
    const bf16* Bg = B + (size_t)(bcol + sr) * K + sc;

    f32x4 acc[MFR][4] = {};

    auto stage = [&](int bi, int kt) {
        char* al = lds + bi * BUF + tid * 16;
        #pragma unroll
        for (int it = 0; it < AISS; ++it)
            gload_lds16(Ag + (size_t)(it * 128) * K + kt * 32, al + it * 8192);
        char* bl = lds + bi * BUF + A_SZ + tid * 16;
        #pragma unroll
        for (int it = 0; it < 2; ++it)
            gload_lds16(Bg + (size_t)(it * 128) * K + kt * 32, bl + it * 8192);
    };

    const int NT = K >> 5;
    stage(0, 0);
    stage(1, 1);
    int cur = 0, nxt = 2;                   // nxt = buffer for tile t+2
    for (int t = 0; t < NT; ++t) {
        if (t + 2 < NT) {
            stage(nxt, t + 2);
            if constexpr (BM == 256) asm volatile("s_waitcnt vmcnt(8)" ::: "memory");
            else                     asm volatile("s_waitcnt vmcnt(6)" ::: "memory");
        } else if (t + 2 == NT) {
            if constexpr (BM == 256) asm volatile("s_waitcnt vmcnt(4)" ::: "memory");
            else                     asm volatile("s_waitcnt vmcnt(3)" ::: "memory");
        } else {
            asm volatile("s_waitcnt vmcnt(0)" ::: "memory");
        }
        __builtin_amdgcn_s_barrier();       // tile t fully in LDS for all waves

        const char* base = lds + cur * BUF;
        const char* ab = base + (wr * (BM / 2) + lo) * 64 + hi * 16;
        const char* bb = base + A_SZ + (wc * 64 + lo) * 64 + hi * 16;
        bf16x8 af[MFR], bfv[4];
        #pragma unroll
        for (int m = 0; m < MFR; ++m) af[m] = *(const bf16x8*)(ab + m * 1024);
        #pragma unroll
        for (int n = 0; n < 4; ++n) bfv[n] = *(const bf16x8*)(bb + n * 1024);
        __builtin_amdgcn_s_setprio(1);
        #pragma unroll
        for (int m = 0; m < MFR; ++m)
            #pragma unroll
            for (int n = 0; n < 4; ++n)
                acc[m][n] = __builtin_amdgcn_mfma_f32_16x16x32_bf16(af[m], bfv[n], acc[m][n], 0, 0, 0);
        __builtin_amdgcn_s_setprio(0);
        __builtin_amdgcn_s_barrier();       // all reads of buf(cur) done -> reusable

        cur = (cur == 2) ? 0 : cur + 1;
        nxt = (nxt == 2) ? 0 : nxt + 1;
    }

    // ---- epilogue
    float* outF = (float*)OutP;
    bf16*  outB = (bf16*)OutP;
    #pragma unroll
    for (int n = 0; n < 4; ++n) {
        const int col = bcol + wc * 64 + n * 16 + lo;
        float bv = 0.f;
        if (EPI == 1 || EPI == 3) bv = bias[col];
        #pragma unroll
        for (int m = 0; m < MFR; ++m) {
            #pragma unroll
            for (int rr = 0; rr < 4; ++rr) {
                const int row = brow + wr * (BM / 2) + m * 16 + hi * 4 + rr;
                float v = acc[m][n][rr];
                if (EPI == 0) {
                    outB[(size_t)row * N + col] = (bf16)v;
                } else if (EPI == 1) {
                    v += bv;
                    v = 0.5f * v * (1.0f + erff(v * 0.70710678118654752f));
                    outB[(size_t)row * N + col] = (bf16)v;
                } else if (EPI == 2) {
                    outF[(size_t)row * N + col] = res[(size_t)row * N + col] + v;
                } else {
                    outF[(size_t)row * N + col] = res[(size_t)row * N + col] + v + bv;
                }
            }
        }
    }
}

// ---------------------------------------------------------------- RoPE + GQA scatter
// qkv: (B*T, 3072) bf16  ->  Q (B,16,T,128), K (B,4,T,128), Vt (B,4,128,T)
__global__ __launch_bounds__(256) void rope_scatter(const bf16* __restrict__ qkv,
                                                    const float* __restrict__ cosb,
                                                    const float* __restrict__ sinb,
                                                    bf16* __restrict__ Q,
                                                    bf16* __restrict__ Kg,
                                                    bf16* __restrict__ Vt) {
    const int tid = threadIdx.x;
    const int row = blockIdx.x;          // b*T + t
    const int b = row >> 11, t = row & 2047;
    const bf16* src = qkv + (size_t)row * 3072;
    for (int i = tid; i < 1536; i += 256) {
        int slot = i >> 6;               // 0..23  = g*6 + m
        int d = i & 63;
        int g = slot / 6, m = slot - g * 6;
        float v1 = (float)src[slot * 128 + d];
        float v2 = (float)src[slot * 128 + d + 64];
        float o1, o2;
        if (m < 5) {
            float c1 = cosb[t * 128 + d],      s1 = sinb[t * 128 + d];
            float c2 = cosb[t * 128 + d + 64], s2 = sinb[t * 128 + d + 64];
            o1 = v1 * c1 - v2 * s1;
            o2 = v2 * c2 + v1 * s2;
        } else {
            o1 = v1; o2 = v2;
        }
        if (m < 4) {
            int hh = g * 4 + m;
            size_t base = ((size_t)(b * 16 + hh) * 2048 + t) * 128;
            Q[base + d] = (bf16)o1;
            Q[base + d + 64] = (bf16)o2;
        } else if (m == 4) {
            size_t base = ((size_t)(b * 4 + g) * 2048 + t) * 128;
            Kg[base + d] = (bf16)o1;
            Kg[base + d + 64] = (bf16)o2;
        } else {
            size_t base = (size_t)(b * 4 + g) * 128;
            Vt[(base + d) * 2048 + t] = (bf16)o1;
            Vt[(base + d + 64) * 2048 + t] = (bf16)o2;
        }
    }
}

// ---------------------------------------------------------------- causal flash attention
// Q (B,16,T,128), K (B,4,T,128), Vt (B,4,128,T)  ->  Y (B,T,16*128) bf16
__global__ __launch_bounds__(256) void attn_kernel(const bf16* __restrict__ Q,
                                                   const bf16* __restrict__ Kg,
                                                   const bf16* __restrict__ Vt,
                                                   bf16* __restrict__ Y) {
    __shared__ __align__(16) bf16 Ks[64 * 128];       // swizzled [t][d]
    __shared__ __align__(16) bf16 Vs[128 * 64];       // swizzled [d][t]
    __shared__ __align__(16) bf16 Ps[4][16 * 80];     // per-wave P [q][t] pad 80

    const int tid = threadIdx.x;
    const int lane = tid & 63, w = tid >> 6;
    const int lo = lane & 15, hi = lane >> 4;
    const int q0 = blockIdx.x * 64;
    const int bh = blockIdx.y;
    const int b = bh >> 4, h = bh & 15;
    const int g = h >> 2;

    // Q fragments (A operand), rows = q0 + w*16 + lo
    bf16x8 qf[4];
    {
        const size_t qbase = ((size_t)bh * 2048 + q0 + w * 16 + lo) * 128;
        #pragma unroll
        for (int dd = 0; dd < 4; ++dd)
            qf[dd] = *(const bf16x8*)(Q + qbase + dd * 32 + hi * 8);
    }
    const bf16* Kbase = Kg + (size_t)(b * 4 + g) * 2048 * 128;
    const bf16* Vbase = Vt + (size_t)(b * 4 + g) * 128 * 2048;

    float m_r[4], l_r[4];
    f32x4 oacc[8] = {};
    #pragma unroll
    for (int r = 0; r < 4; ++r) { m_r[r] = -1e30f; l_r[r] = 0.f; }

    const int ktlast = blockIdx.x;
    const float scale = 0.08838834764831845f;   // 1/sqrt(128)
    bf16* pw = &Ps[w][0];

    for (int kt = 0; kt <= ktlast; ++kt) {
        // ---- stage K (64x128) and V^T (128x64), XOR-swizzled
        #pragma unroll
        for (int it = 0; it < 4; ++it) {
            int ob = (it * 256 + tid) * 16;
            int r  = ob >> 8, cb = ob & 255;
            bf16x8 kv = *(const bf16x8*)(Kbase + (size_t)(kt * 64 + r) * 128 + (cb >> 1));
            *(bf16x8*)((char*)Ks + r * 256 + (cb ^ ((r & 7) << 4))) = kv;
            int dv = ob >> 7, cv = ob & 127;
            bf16x8 vv = *(const bf16x8*)(Vbase + (size_t)dv * 2048 + kt * 64 + (cv >> 1));
            *(bf16x8*)((char*)Vs + dv * 128 + (cv ^ ((dv & 7) << 4))) = vv;
        }
        __syncthreads();

        // ---- S = Q K^T : 4 t-subtiles of 16
        f32x4 sj[4];
        #pragma unroll
        for (int j = 0; j < 4; ++j) {
            f32x4 a = {};
            int r = j * 16 + lo;
            #pragma unroll
            for (int dd = 0; dd < 4; ++dd) {
                int cb = dd * 64 + hi * 16;
                bf16x8 kf = *(const bf16x8*)((const char*)Ks + r * 256 + (cb ^ ((r & 7) << 4)));
                a = __builtin_amdgcn_mfma_f32_16x16x32_bf16(qf[dd], kf, a, 0, 0, 0);
            }
            sj[j] = a;
        }

        // ---- scale + causal mask
        float sv[4][4];
        const bool diag = (kt == ktlast);
        #pragma unroll
        for (int j = 0; j < 4; ++j)
            #pragma unroll
            for (int rr = 0; rr < 4; ++rr) {
                float v = sj[j][rr] * scale;
                if (diag) {
                    int tg = kt * 64 + j * 16 + lo;
                    int qg = q0 + w * 16 + hi * 4 + rr;
                    if (tg > qg) v = -1e30f;
                }
                sv[j][rr] = v;
            }

        // ---- online softmax (rows live across lanes lo=0..15 of same hi group)
        float mx[4];
        #pragma unroll
        for (int rr = 0; rr < 4; ++rr) {
            float m0 = fmaxf(fmaxf(sv[0][rr], sv[1][rr]), fmaxf(sv[2][rr], sv[3][rr]));
            #pragma unroll
            for (int off = 8; off; off >>= 1) m0 = fmaxf(m0, __shfl_xor(m0, off, 16));
            mx[rr] = m0;
        }
        float p[4][4];
        float rs[4], al[4];
        #pragma unroll
        for (int rr = 0; rr < 4; ++rr) {
            float mnew = fmaxf(m_r[rr], mx[rr]);
            #pragma unroll
            for (int j = 0; j < 4; ++j)
                p[j][rr] = exp2f((sv[j][rr] - mnew) * LOG2E);
            float s0 = p[0][rr] + p[1][rr] + p[2][rr] + p[3][rr];
            #pragma unroll
            for (int off = 8; off; off >>= 1) s0 += __shfl_xor(s0, off, 16);
            rs[rr] = s0;
            al[rr] = exp2f((m_r[rr] - mnew) * LOG2E);
            l_r[rr] = l_r[rr] * al[rr] + rs[rr];
            m_r[rr] = mnew;
        }
        #pragma unroll
        for (int dn = 0; dn < 8; ++dn)
            #pragma unroll
            for (int rr = 0; rr < 4; ++rr) oacc[dn][rr] *= al[rr];

        // ---- write P to per-wave LDS [16 q][80 t]
        #pragma unroll
        for (int j = 0; j < 4; ++j)
            #pragma unroll
            for (int rr = 0; rr < 4; ++rr)
                pw[(hi * 4 + rr) * 80 + j * 16 + lo] = (bf16)p[j][rr];

        // ---- O += P V
        #pragma unroll
        for (int tc = 0; tc < 2; ++tc) {
            bf16x8 pf = *(const bf16x8*)(pw + lo * 80 + tc * 32 + hi * 8);
            #pragma unroll
            for (int dn = 0; dn < 8; ++dn) {
                int rv = dn * 16 + lo;
                int cv = tc * 64 + hi * 16;
                bf16x8 vf = *(const bf16x8*)((const char*)Vs + rv * 128 + (cv ^ ((rv & 7) << 4)));
                oacc[dn] = __builtin_amdgcn_mfma_f32_16x16x32_bf16(pf, vf, oacc[dn], 0, 0, 0);
            }
        }
        __syncthreads();
    }

    // ---- epilogue: Y[(b, q, h*128 + d)] = O / l
    #pragma unroll
    for (int dn = 0; dn < 8; ++dn)
        #pragma unroll
        for (int rr = 0; rr < 4; ++rr) {
            int qg = q0 + w * 16 + hi * 4 + rr;
            Y[((size_t)b * 2048 + qg) * 2048 + h * 128 + dn * 16 + lo] =
                (bf16)(oacc[dn][rr] / l_r[rr]);
        }
}

// ---------------------------------------------------------------- launch
extern "C" void kernel_launch(void* const* d_in, const int* in_sizes, int n_in,
                              void* d_out, int out_size, void* d_ws, size_t ws_size,
                              hipStream_t stream) {
    const float* x      = (const float*)d_in[0];
    const float* cosb   = (const float*)d_in[1];
    const float* sinb   = (const float*)d_in[2];
    const float* ln1_w  = (const float*)d_in[4];
    const float* ln1_b  = (const float*)d_in[5];
    const float* qkv_w  = (const float*)d_in[6];
    const float* proj_w = (const float*)d_in[7];
    const float* ln2_w  = (const float*)d_in[8];
    const float* ln2_b  = (const float*)d_in[9];
    const float* fc1_w  = (const float*)d_in[10];
    const float* fc1_b  = (const float*)d_in[11];
    const float* fc2_w  = (const float*)d_in[12];
    const float* fc2_b  = (const float*)d_in[13];
    float* out = (float*)d_out;

    char* ws = (char*)d_ws;
    bf16*  w_qkv  = (bf16*)(ws + 0ull);            // 3072x2048
    bf16*  w_proj = (bf16*)(ws + 12582912ull);     // 2048x2048
    bf16*  w_fc1  = (bf16*)(ws + 20971520ull);     // 8192x2048
    bf16*  w_fc2  = (bf16*)(ws + 54525952ull);     // 2048x8192
    float* x2     = (float*)(ws + 88080384ull);    // 4096x2048 f32
    bf16*  lnout  = (bf16*)(ws + 121634816ull);    // 4096x2048
    char*  R      = ws + 138412032ull;             // aliased region (67.1 MB)
    bf16*  qkvo = (bf16*)(R);                      // 4096x3072
    bf16*  Qb   = (bf16*)(R + 25165824ull);        // 2,16,2048,128
    bf16*  Kb   = (bf16*)(R + 41943040ull);        // 2,4,2048,128
    bf16*  Vtb  = (bf16*)(R + 46137344ull);        // 2,4,128,2048
    bf16*  Yb   = (bf16*)(R + 50331648ull);        // 4096x2048
    bf16*  mlp  = (bf16*)(R);                      // 4096x8192 (aliases all above)

    constexpr int LDS256 = 3 * (256 * 64 + 256 * 64);   // 98304
    constexpr int LDS128 = 3 * (128 * 64 + 256 * 64);   // 73728

    cvt_bf16<<<6144,  256, 0, stream>>>(qkv_w,  w_qkv,  3072 * 2048);
    cvt_bf16<<<4096,  256, 0, stream>>>(proj_w, w_proj, 2048 * 2048);
    cvt_bf16<<<16384, 256, 0, stream>>>(fc1_w,  w_fc1,  8192 * 2048);
    cvt_bf16<<<16384, 256, 0, stream>>>(fc2_w,  w_fc2,  2048 * 8192);

    ln_kernel<<<4096, 256, 0, stream>>>(x, ln1_w, ln1_b, lnout);

    gemm3<128, 0><<<384, 512, LDS128, stream>>>(lnout, w_qkv, qkvo, nullptr, nullptr,
                                                4096, 3072, 2048);

    rope_scatter<<<4096, 256, 0, stream>>>(qkvo, cosb, sinb, Qb, Kb, Vtb);

    attn_kernel<<<dim3(32, 32), 256, 0, stream>>>(Qb, Kb, Vtb, Yb);

    gemm3<128, 2><<<256, 512, LDS128, stream>>>(Yb, w_proj, x2, nullptr, x,
                                                4096, 2048, 2048);

    ln_kernel<<<4096, 256, 0, stream>>>(x2, ln2_w, ln2_b, lnout);

    gemm3<256, 1><<<512, 512, LDS256, stream>>>(lnout, w_fc1, mlp, fc1_b, nullptr,
                                                4096, 8192, 2048);

    gemm3<128, 3><<<256, 512, LDS128, stream>>>(mlp, w_fc2, out, fc2_b, x2,
                                                4096, 2048, 8192);
}

// Round 4
// 783.063 us; speedup vs baseline: 1.0699x; 1.0064x over previous
//
#include <hip/hip_runtime.h>

typedef __bf16 bf16;
typedef __bf16 bf16x8 __attribute__((ext_vector_type(8)));
typedef __bf16 bf16x4 __attribute__((ext_vector_type(4)));
typedef float  f32x4  __attribute__((ext_vector_type(4)));

#define LOG2E 1.4426950408889634f

// ---------------------------------------------------------------- helpers
__device__ __forceinline__ void gload_lds16(const void* g, void* l) {
    __builtin_amdgcn_global_load_lds(
        (__attribute__((address_space(1))) const void*)g,
        (__attribute__((address_space(3))) void*)l, 16, 0, 0);
}

template <int N> __device__ __forceinline__ void vmwait() {
    if constexpr (N < 0) {}
    else if constexpr (N == 0)  asm volatile("s_waitcnt vmcnt(0)" ::: "memory");
    else if constexpr (N == 1)  asm volatile("s_waitcnt vmcnt(1)" ::: "memory");
    else if constexpr (N == 2)  asm volatile("s_waitcnt vmcnt(2)" ::: "memory");
    else if constexpr (N == 3)  asm volatile("s_waitcnt vmcnt(3)" ::: "memory");
    else if constexpr (N == 4)  asm volatile("s_waitcnt vmcnt(4)" ::: "memory");
    else if constexpr (N == 6)  asm volatile("s_waitcnt vmcnt(6)" ::: "memory");
    else if constexpr (N == 7)  asm volatile("s_waitcnt vmcnt(7)" ::: "memory");
    else if constexpr (N == 8)  asm volatile("s_waitcnt vmcnt(8)" ::: "memory");
    else if constexpr (N == 10) asm volatile("s_waitcnt vmcnt(10)" ::: "memory");
}

#define BAR() { asm volatile("" ::: "memory"); __builtin_amdgcn_s_barrier(); asm volatile("" ::: "memory"); }

// ---------------------------------------------------------------- f32 -> bf16 weight convert
__global__ __launch_bounds__(256) void cvt_bf16(const float* __restrict__ src,
                                                bf16* __restrict__ dst, int n) {
    int i = (blockIdx.x * 256 + threadIdx.x) * 4;
    if (i + 3 < n) {
        float4 v = *(const float4*)(src + i);
        bf16x4 o;
        o[0] = (bf16)v.x; o[1] = (bf16)v.y; o[2] = (bf16)v.z; o[3] = (bf16)v.w;
        *(bf16x4*)(dst + i) = o;
    }
}

// ---------------------------------------------------------------- LayerNorm (f32 in, bf16 out), row = 2048
__global__ __launch_bounds__(256) void ln_kernel(const float* __restrict__ x,
                                                 const float* __restrict__ wgt,
                                                 const float* __restrict__ bias,
                                                 bf16* __restrict__ out) {
    __shared__ float red[8];
    const int tid = threadIdx.x;
    const int lane = tid & 63, w = tid >> 6;
    const size_t row = blockIdx.x;
    const float4* xr = (const float4*)(x + row * 2048);
    float4 v0 = xr[tid];
    float4 v1 = xr[tid + 256];
    float s = v0.x + v0.y + v0.z + v0.w + v1.x + v1.y + v1.z + v1.w;
    float q = v0.x*v0.x + v0.y*v0.y + v0.z*v0.z + v0.w*v0.w
            + v1.x*v1.x + v1.y*v1.y + v1.z*v1.z + v1.w*v1.w;
    #pragma unroll
    for (int off = 32; off; off >>= 1) {
        s += __shfl_xor(s, off);
        q += __shfl_xor(q, off);
    }
    if (lane == 0) { red[w] = s; red[4 + w] = q; }
    __syncthreads();
    float S  = red[0] + red[1] + red[2] + red[3];
    float Q2 = red[4] + red[5] + red[6] + red[7];
    float mu = S * (1.0f / 2048.0f);
    float var = Q2 * (1.0f / 2048.0f) - mu * mu;
    float rstd = rsqrtf(var + 1e-5f);

    bf16* orow = out + row * 2048;
    int c0 = tid * 4;
    float vv[8] = {v0.x, v0.y, v0.z, v0.w, v1.x, v1.y, v1.z, v1.w};
    bf16x4 o;
    #pragma unroll
    for (int k = 0; k < 4; ++k)
        o[k] = (bf16)((vv[k] - mu) * rstd * wgt[c0 + k] + bias[c0 + k]);
    *(bf16x4*)(orow + c0) = o;
    #pragma unroll
    for (int k = 0; k < 4; ++k)
        o[k] = (bf16)((vv[4 + k] - mu) * rstd * wgt[1024 + c0 + k] + bias[1024 + c0 + k]);
    *(bf16x4*)(orow + 1024 + c0) = o;
}

// ---------------------------------------------------------------- GEMM  C[M,N] = A[M,K] * B[N,K]^T  (both bf16)
// 8-phase schedule, BM x 256 tile, BK=64, 8 waves (2M x 4N), 512 threads.
// LDS: 2 buffers x {A: 2 halves, B: 2 halves} in K-major 1KB-block layout:
//   block (ks, gf) of a half holds rows gf*16+lo, cols ks*32+hi*8 (16B per lane)
//   -> fragment ds_read_b128 is one contiguous 1KB per wave: zero bank conflict.
// Staged via global_load_lds with per-lane permuted GLOBAL source (LDS dest linear).
// Per phase: {ds-read subtile | stage one half-tile | counted vmcnt | barrier |
//             setprio(1) 16/8 MFMA setprio(0) | barrier}.
// EPI: 0 = bf16 out, 1 = +bias exact GELU bf16, 2 = res+acc->f32, 3 = res+acc+bias->f32
template <int BM, int EPI>
__global__ __launch_bounds__(512, 2) void gemm8(const bf16* __restrict__ A,
                                                const bf16* __restrict__ B,
                                                void* __restrict__ OutP,
                                                const float* __restrict__ bias,
                                                const float* __restrict__ res,
                                                int M, int N, int K) {
    constexpr int AHALF = BM * 64;           // bytes per A half-tile (BM/2 x 64 bf16)
    constexpr int ASZ   = 2 * AHALF;
    constexpr int BHALF = 16384;             // 128 x 64 bf16
    constexpr int BUFSZ = ASZ + 32768;
    constexpr int MFRH  = BM / 64;           // A frags per wave per half (4 / 2)
    constexpr int MFT   = BM / 32;           // total m frags per wave (8 / 4)
    constexpr int LA    = BM / 128;          // A loads per half-tile per thread (2 / 1)
    constexpr int W_A   = 3 * LA + 4;        // steady waits
    constexpr int W_B   = 2 * LA + 6;
    constexpr int WF1   = 2 * LA + 4;        // final-iteration waits
    constexpr int WF3   = LA + 2;
    constexpr int WF4   = LA;
    extern __shared__ __align__(16) char lds[];

    const int tid = threadIdx.x;
    const int lane = tid & 63;
    const int w = tid >> 6, wr = w >> 2, wc = w & 3;
    const int lo = lane & 15, hi = lane >> 4;
    const int ln16 = lane * 16;

    // ---- block swizzle: XCD-bijective, then column-groups of 4 (M-major inside)
    const int nwg = gridDim.x;
    const int bid = blockIdx.x;
    const int q = nwg >> 3, r = nwg & 7, xcd = bid & 7, off = bid >> 3;
    const int s = (xcd < r ? xcd * (q + 1) : r * (q + 1) + (xcd - r) * q) + off;
    const int MB = M / BM;
    const int per = MB * 4;
    const int grp = s / per, t2 = s - grp * per;
    const int brow = (t2 % MB) * BM;
    const int bcol = (grp * 4 + t2 / MB) * 256;

    // ---- staging source/dest (per-lane permuted global, linear LDS)
    const bf16* Agp = A + (size_t)(brow + (BM == 256 ? w : (w & 3)) * 16 + lo) * K + hi * 8;
    const bf16* Bgp = B + (size_t)(bcol + w * 16 + lo) * K + hi * 8;
    const int adst = (BM == 256 ? w : ((w >> 2) * 4 + (w & 3))) * 1024 + ln16;
    const int bdst = w * 1024 + ln16;

    auto stA = [&](int bf, int kt, int h) {
        const bf16* g = Agp + (size_t)h * (BM / 2) * K + kt * 64;
        char* d = lds + bf * BUFSZ + h * AHALF + adst;
        if constexpr (BM == 256) {
            gload_lds16(g, d);
            gload_lds16(g + 32, d + 8192);
        } else {
            gload_lds16(g + (w >> 2) * 32, d);
        }
    };
    auto stB = [&](int bf, int kt, int h) {
        const bf16* g = Bgp + (size_t)h * 128 * K + kt * 64;
        char* d = lds + bf * BUFSZ + ASZ + h * BHALF + bdst;
        gload_lds16(g, d);
        gload_lds16(g + 32, d + 8192);
    };

    bf16x8 af[MFRH][2], b0[2][2], b1[2][2];
    f32x4 acc[MFT][4] = {};

#define LDA(BF, MH) { _Pragma("unroll") for (int m = 0; m < MFRH; ++m) { \
    _Pragma("unroll") for (int ks = 0; ks < 2; ++ks) { \
        af[m][ks] = *(const bf16x8*)(lds + (BF) * BUFSZ + (MH) * AHALF + \
                                     ((ks * (BM / 32) + wr * MFRH + m) << 10) + ln16); } } }
#define LDB(BF, NH, BB) { _Pragma("unroll") for (int n = 0; n < 2; ++n) { \
    _Pragma("unroll") for (int ks = 0; ks < 2; ++ks) { \
        BB[n][ks] = *(const bf16x8*)(lds + (BF) * BUFSZ + ASZ + (NH) * BHALF + \
                                     ((ks * 8 + wc * 2 + n) << 10) + ln16); } } }
#define MFMAQ(MH, NH, BB) { __builtin_amdgcn_s_setprio(1); \
    _Pragma("unroll") for (int m = 0; m < MFRH; ++m) { \
    _Pragma("unroll") for (int n = 0; n < 2; ++n) { \
    _Pragma("unroll") for (int ks = 0; ks < 2; ++ks) { \
        acc[(MH) * MFRH + m][(NH) * 2 + n] = __builtin_amdgcn_mfma_f32_16x16x32_bf16( \
            af[m][ks], BB[n][ks], acc[(MH) * MFRH + m][(NH) * 2 + n], 0, 0, 0); } } } \
    __builtin_amdgcn_s_setprio(0); }

    const int NIT = (K >> 6) >> 1;
    // ---- prologue: tiles 0 (A0,B0,B1,A1) and 1 (A0,B0,B1); tile1.A1 staged by iter0.
    stA(0, 0, 0); stB(0, 0, 0); stB(0, 0, 1); stA(0, 0, 1);
    stA(1, 1, 0); stB(1, 1, 0); stB(1, 1, 1);
    vmwait<W_B>(); BAR();

    #pragma unroll 1
    for (int T = 0; T < NIT - 1; ++T) {
        const int t = 2 * T;
        LDA(0, 0) LDB(0, 0, b0) stA(1, t + 1, 1); vmwait<W_A>(); BAR(); MFMAQ(0, 0, b0) BAR();
        LDB(0, 1, b1)           stA(0, t + 2, 0); vmwait<W_A>(); BAR(); MFMAQ(0, 1, b1) BAR();
        LDA(0, 1)               stB(0, t + 2, 0);                BAR(); MFMAQ(1, 0, b0) BAR();
                                stB(0, t + 2, 1); vmwait<W_B>(); BAR(); MFMAQ(1, 1, b1) BAR();
        LDA(1, 0) LDB(1, 0, b0) stA(0, t + 2, 1); vmwait<W_A>(); BAR(); MFMAQ(0, 0, b0) BAR();
        LDB(1, 1, b1)           stA(1, t + 3, 0); vmwait<W_A>(); BAR(); MFMAQ(0, 1, b1) BAR();
        LDA(1, 1)               stB(1, t + 3, 0);                BAR(); MFMAQ(1, 0, b0) BAR();
                                stB(1, t + 3, 1); vmwait<W_B>(); BAR(); MFMAQ(1, 1, b1) BAR();
    }
    {   // ---- final iteration: no stages except (t+1).A1
        const int t = 2 * (NIT - 1);
        LDA(0, 0) LDB(0, 0, b0) stA(1, t + 1, 1); vmwait<W_A>(); BAR(); MFMAQ(0, 0, b0) BAR();
        LDB(0, 1, b1)                             vmwait<WF1>(); BAR(); MFMAQ(0, 1, b1) BAR();
        LDA(0, 1)                                                BAR(); MFMAQ(1, 0, b0) BAR();
                                                  vmwait<WF3>(); BAR(); MFMAQ(1, 1, b1) BAR();
        LDA(1, 0) LDB(1, 0, b0)                   vmwait<WF4>(); BAR(); MFMAQ(0, 0, b0) BAR();
        LDB(1, 1, b1)                             vmwait<0>();   BAR(); MFMAQ(0, 1, b1) BAR();
        LDA(1, 1)                                                BAR(); MFMAQ(1, 0, b0) BAR();
                                                                        MFMAQ(1, 1, b1)
    }
#undef LDA
#undef LDB
#undef MFMAQ

    // ---- epilogue: row = brow + mh*(BM/2) + wr*(BM/4) + ml*16 + hi*4 + rr
    //                col = bcol + nh*128  + wc*32     + nl*16 + lo
    float* outF = (float*)OutP;
    bf16*  outB = (bf16*)OutP;
    #pragma unroll
    for (int n = 0; n < 4; ++n) {
        const int col = bcol + (n >> 1) * 128 + wc * 32 + (n & 1) * 16 + lo;
        float bv = 0.f;
        if (EPI == 1 || EPI == 3) bv = bias[col];
        #pragma unroll
        for (int m = 0; m < MFT; ++m) {
            const int mh = m / MFRH, ml = m % MFRH;
            const int rb = brow + mh * (BM / 2) + wr * (BM / 4) + ml * 16 + hi * 4;
            #pragma unroll
            for (int rr = 0; rr < 4; ++rr) {
                const int row = rb + rr;
                float v = acc[m][n][rr];
                if (EPI == 0) {
                    outB[(size_t)row * N + col] = (bf16)v;
                } else if (EPI == 1) {
                    v += bv;
                    v = 0.5f * v * (1.0f + erff(v * 0.70710678118654752f));
                    outB[(size_t)row * N + col] = (bf16)v;
                } else if (EPI == 2) {
                    outF[(size_t)row * N + col] = res[(size_t)row * N + col] + v;
                } else {
                    outF[(size_t)row * N + col] = res[(size_t)row * N + col] + v + bv;
                }
            }
        }
    }
}

// ---------------------------------------------------------------- RoPE + GQA scatter
// qkv: (B*T, 3072) bf16  ->  Q (B,16,T,128), K (B,4,T,128), Vt (B,4,128,T)
__global__ __launch_bounds__(256) void rope_scatter(const bf16* __restrict__ qkv,
                                                    const float* __restrict__ cosb,
                                                    const float* __restrict__ sinb,
                                                    bf16* __restrict__ Q,
                                                    bf16* __restrict__ Kg,
                                                    bf16* __restrict__ Vt) {
    const int tid = threadIdx.x;
    const int row = blockIdx.x;          // b*T + t
    const int b = row >> 11, t = row & 2047;
    const bf16* src = qkv + (size_t)row * 3072;
    for (int i = tid; i < 1536; i += 256) {
        int slot = i >> 6;               // 0..23  = g*6 + m
        int d = i & 63;
        int g = slot / 6, m = slot - g * 6;
        float v1 = (float)src[slot * 128 + d];
        float v2 = (float)src[slot * 128 + d + 64];
        float o1, o2;
        if (m < 5) {
            float c1 = cosb[t * 128 + d],      s1 = sinb[t * 128 + d];
            float c2 = cosb[t * 128 + d + 64], s2 = sinb[t * 128 + d + 64];
            o1 = v1 * c1 - v2 * s1;
            o2 = v2 * c2 + v1 * s2;
        } else {
            o1 = v1; o2 = v2;
        }
        if (m < 4) {
            int hh = g * 4 + m;
            size_t base = ((size_t)(b * 16 + hh) * 2048 + t) * 128;
            Q[base + d] = (bf16)o1;
            Q[base + d + 64] = (bf16)o2;
        } else if (m == 4) {
            size_t base = ((size_t)(b * 4 + g) * 2048 + t) * 128;
            Kg[base + d] = (bf16)o1;
            Kg[base + d + 64] = (bf16)o2;
        } else {
            size_t base = (size_t)(b * 4 + g) * 128;
            Vt[(base + d) * 2048 + t] = (bf16)o1;
            Vt[(base + d + 64) * 2048 + t] = (bf16)o2;
        }
    }
}

// ---------------------------------------------------------------- causal flash attention
// Q (B,16,T,128), K (B,4,T,128), Vt (B,4,128,T)  ->  Y (B,T,16*128) bf16
__global__ __launch_bounds__(256) void attn_kernel(const bf16* __restrict__ Q,
                                                   const bf16* __restrict__ Kg,
                                                   const bf16* __restrict__ Vt,
                                                   bf16* __restrict__ Y) {
    __shared__ __align__(16) bf16 Ks[64 * 128];       // swizzled [t][d]
    __shared__ __align__(16) bf16 Vs[128 * 64];       // swizzled [d][t]
    __shared__ __align__(16) bf16 Ps[4][16 * 80];     // per-wave P [q][t] pad 80

    const int tid = threadIdx.x;
    const int lane = tid & 63, w = tid >> 6;
    const int lo = lane & 15, hi = lane >> 4;
    const int q0 = blockIdx.x * 64;
    const int bh = blockIdx.y;
    const int b = bh >> 4, h = bh & 15;
    const int g = h >> 2;

    // Q fragments (A operand), rows = q0 + w*16 + lo
    bf16x8 qf[4];
    {
        const size_t qbase = ((size_t)bh * 2048 + q0 + w * 16 + lo) * 128;
        #pragma unroll
        for (int dd = 0; dd < 4; ++dd)
            qf[dd] = *(const bf16x8*)(Q + qbase + dd * 32 + hi * 8);
    }
    const bf16* Kbase = Kg + (size_t)(b * 4 + g) * 2048 * 128;
    const bf16* Vbase = Vt + (size_t)(b * 4 + g) * 128 * 2048;

    float m_r[4], l_r[4];
    f32x4 oacc[8] = {};
    #pragma unroll
    for (int r = 0; r < 4; ++r) { m_r[r] = -1e30f; l_r[r] = 0.f; }

    const int ktlast = blockIdx.x;
    const float scale = 0.08838834764831845f;   // 1/sqrt(128)
    bf16* pw = &Ps[w][0];

    for (int kt = 0; kt <= ktlast; ++kt) {
        // ---- stage K (64x128) and V^T (128x64), XOR-swizzled
        #pragma unroll
        for (int it = 0; it < 4; ++it) {
            int ob = (it * 256 + tid) * 16;
            int r  = ob >> 8, cb = ob & 255;
            bf16x8 kv = *(const bf16x8*)(Kbase + (size_t)(kt * 64 + r) * 128 + (cb >> 1));
            *(bf16x8*)((char*)Ks + r * 256 + (cb ^ ((r & 7) << 4))) = kv;
            int dv = ob >> 7, cv = ob & 127;
            bf16x8 vv = *(const bf16x8*)(Vbase + (size_t)dv * 2048 + kt * 64 + (cv >> 1));
            *(bf16x8*)((char*)Vs + dv * 128 + (cv ^ ((dv & 7) << 4))) = vv;
        }
        __syncthreads();

        // ---- S = Q K^T : 4 t-subtiles of 16
        f32x4 sj[4];
        #pragma unroll
        for (int j = 0; j < 4; ++j) {
            f32x4 a = {};
            int r = j * 16 + lo;
            #pragma unroll
            for (int dd = 0; dd < 4; ++dd) {
                int cb = dd * 64 + hi * 16;
                bf16x8 kf = *(const bf16x8*)((const char*)Ks + r * 256 + (cb ^ ((r & 7) << 4)));
                a = __builtin_amdgcn_mfma_f32_16x16x32_bf16(qf[dd], kf, a, 0, 0, 0);
            }
            sj[j] = a;
        }

        // ---- scale + causal mask
        float sv[4][4];
        const bool diag = (kt == ktlast);
        #pragma unroll
        for (int j = 0; j < 4; ++j)
            #pragma unroll
            for (int rr = 0; rr < 4; ++rr) {
                float v = sj[j][rr] * scale;
                if (diag) {
                    int tg = kt * 64 + j * 16 + lo;
                    int qg = q0 + w * 16 + hi * 4 + rr;
                    if (tg > qg) v = -1e30f;
                }
                sv[j][rr] = v;
            }

        // ---- online softmax (rows live across lanes lo=0..15 of same hi group)
        float mx[4];
        #pragma unroll
        for (int rr = 0; rr < 4; ++rr) {
            float m0 = fmaxf(fmaxf(sv[0][rr], sv[1][rr]), fmaxf(sv[2][rr], sv[3][rr]));
            #pragma unroll
            for (int off = 8; off; off >>= 1) m0 = fmaxf(m0, __shfl_xor(m0, off, 16));
            mx[rr] = m0;
        }
        float p[4][4];
        float rs[4], al[4];
        #pragma unroll
        for (int rr = 0; rr < 4; ++rr) {
            float mnew = fmaxf(m_r[rr], mx[rr]);
            #pragma unroll
            for (int j = 0; j < 4; ++j)
                p[j][rr] = exp2f((sv[j][rr] - mnew) * LOG2E);
            float s0 = p[0][rr] + p[1][rr] + p[2][rr] + p[3][rr];
            #pragma unroll
            for (int off = 8; off; off >>= 1) s0 += __shfl_xor(s0, off, 16);
            rs[rr] = s0;
            al[rr] = exp2f((m_r[rr] - mnew) * LOG2E);
            l_r[rr] = l_r[rr] * al[rr] + rs[rr];
            m_r[rr] = mnew;
        }
        #pragma unroll
        for (int dn = 0; dn < 8; ++dn)
            #pragma unroll
            for (int rr = 0; rr < 4; ++rr) oacc[dn][rr] *= al[rr];

        // ---- write P to per-wave LDS [16 q][80 t]
        #pragma unroll
        for (int j = 0; j < 4; ++j)
            #pragma unroll
            for (int rr = 0; rr < 4; ++rr)
                pw[(hi * 4 + rr) * 80 + j * 16 + lo] = (bf16)p[j][rr];

        // ---- O += P V
        #pragma unroll
        for (int tc = 0; tc < 2; ++tc) {
            bf16x8 pf = *(const bf16x8*)(pw + lo * 80 + tc * 32 + hi * 8);
            #pragma unroll
            for (int dn = 0; dn < 8; ++dn) {
                int rv = dn * 16 + lo;
                int cv = tc * 64 + hi * 16;
                bf16x8 vf = *(const bf16x8*)((const char*)Vs + rv * 128 + (cv ^ ((rv & 7) << 4)));
                oacc[dn] = __builtin_amdgcn_mfma_f32_16x16x32_bf16(pf, vf, oacc[dn], 0, 0, 0);
            }
        }
        __syncthreads();
    }

    // ---- epilogue: Y[(b, q, h*128 + d)] = O / l
    #pragma unroll
    for (int dn = 0; dn < 8; ++dn)
        #pragma unroll
        for (int rr = 0; rr < 4; ++rr) {
            int qg = q0 + w * 16 + hi * 4 + rr;
            Y[((size_t)b * 2048 + qg) * 2048 + h * 128 + dn * 16 + lo] =
                (bf16)(oacc[dn][rr] / l_r[rr]);
        }
}

// ---------------------------------------------------------------- launch
extern "C" void kernel_launch(void* const* d_in, const int* in_sizes, int n_in,
                              void* d_out, int out_size, void* d_ws, size_t ws_size,
                              hipStream_t stream) {
    const float* x      = (const float*)d_in[0];
    const float* cosb   = (const float*)d_in[1];
    const float* sinb   = (const float*)d_in[2];
    const float* ln1_w  = (const float*)d_in[4];
    const float* ln1_b  = (const float*)d_in[5];
    const float* qkv_w  = (const float*)d_in[6];
    const float* proj_w = (const float*)d_in[7];
    const float* ln2_w  = (const float*)d_in[8];
    const float* ln2_b  = (const float*)d_in[9];
    const float* fc1_w  = (const float*)d_in[10];
    const float* fc1_b  = (const float*)d_in[11];
    const float* fc2_w  = (const float*)d_in[12];
    const float* fc2_b  = (const float*)d_in[13];
    float* out = (float*)d_out;

    char* ws = (char*)d_ws;
    bf16*  w_qkv  = (bf16*)(ws + 0ull);            // 3072x2048
    bf16*  w_proj = (bf16*)(ws + 12582912ull);     // 2048x2048
    bf16*  w_fc1  = (bf16*)(ws + 20971520ull);     // 8192x2048
    bf16*  w_fc2  = (bf16*)(ws + 54525952ull);     // 2048x8192
    float* x2     = (float*)(ws + 88080384ull);    // 4096x2048 f32
    bf16*  lnout  = (bf16*)(ws + 121634816ull);    // 4096x2048
    char*  R      = ws + 138412032ull;             // aliased region (67.1 MB)
    bf16*  qkvo = (bf16*)(R);                      // 4096x3072
    bf16*  Qb   = (bf16*)(R + 25165824ull);        // 2,16,2048,128
    bf16*  Kb   = (bf16*)(R + 41943040ull);        // 2,4,2048,128
    bf16*  Vtb  = (bf16*)(R + 46137344ull);        // 2,4,128,2048
    bf16*  Yb   = (bf16*)(R + 50331648ull);        // 4096x2048
    bf16*  mlp  = (bf16*)(R);                      // 4096x8192 (aliases all above)

    constexpr int LDS256 = 2 * (2 * 256 * 64 + 32768);   // 131072
    constexpr int LDS128 = 2 * (2 * 128 * 64 + 32768);   // 98304

    cvt_bf16<<<6144,  256, 0, stream>>>(qkv_w,  w_qkv,  3072 * 2048);
    cvt_bf16<<<4096,  256, 0, stream>>>(proj_w, w_proj, 2048 * 2048);
    cvt_bf16<<<16384, 256, 0, stream>>>(fc1_w,  w_fc1,  8192 * 2048);
    cvt_bf16<<<16384, 256, 0, stream>>>(fc2_w,  w_fc2,  2048 * 8192);

    ln_kernel<<<4096, 256, 0, stream>>>(x, ln1_w, ln1_b, lnout);

    gemm8<256, 0><<<192, 512, LDS256, stream>>>(lnout, w_qkv, qkvo, nullptr, nullptr,
                                                4096, 3072, 2048);

    rope_scatter<<<4096, 256, 0, stream>>>(qkvo, cosb, sinb, Qb, Kb, Vtb);

    attn_kernel<<<dim3(32, 32), 256, 0, stream>>>(Qb, Kb, Vtb, Yb);

    gemm8<128, 2><<<256, 512, LDS128, stream>>>(Yb, w_proj, x2, nullptr, x,
                                                4096, 2048, 2048);

    ln_kernel<<<4096, 256, 0, stream>>>(x2, ln2_w, ln2_b, lnout);

    gemm8<256, 1><<<512, 512, LDS256, stream>>>(lnout, w_fc1, mlp, fc1_b, nullptr,
                                                4096, 8192, 2048);

    gemm8<128, 3><<<256, 512, LDS128, stream>>>(mlp, w_fc2, out, fc2_b, x2,
                                                4096, 2048, 8192);
}